// Round 3
// baseline (1919.255 us; speedup 1.0000x reference)
//
#include <hip/hip_runtime.h>

#define TS 262144          // TABLE_SIZE = 2^18
#define TMASK (TS - 1)
#define P2 2654435761u
#define P3 805459861u

typedef float nfloat4 __attribute__((ext_vector_type(4)));

// ws layout (XP path):
//   float4 region: levels 0..6 compacted DENSE z-paired tables,
//     entry [x][y][z] = (f0@z, f1@z, f0@z+1c, f1@z+1c)   (z+1 clamped to r1)
//     offsets (float4 units): {0,4096,12096,27721,60489,124489,249489}, total 511633
//   float2 region (starts at float4 index 511633): levels 7..15 transposed hash
//     tables [T,F], 9 * TS entries.
#define N4 511633

// Pre-pass: build compacted/transposed tables in workspace.
__global__ __launch_bounds__(256) void build_kernel(
    const float* __restrict__ dense, const float* __restrict__ tables,
    float4* __restrict__ ws4) {
  int i = blockIdx.x * 256 + threadIdx.x;
  if (i < N4) {
    constexpr int OFF4[8] = {0, 4096, 12096, 27721, 60489, 124489, 249489, N4};
    constexpr int RESL[7] = {16, 20, 25, 32, 40, 50, 64};
    int lvl = 0;
#pragma unroll
    for (int l = 1; l < 7; ++l)
      if (i >= OFF4[l]) lvl = l;
    int j = i - OFF4[lvl];
    int res = RESL[lvl];
    int z = j % res;
    int t = j / res;
    int y = t % res;
    int x = t / res;
    int zp = min(z + 1, res - 1);
    float f0a, f1a, f0b, f1b;
    if (lvl == 0) {
      int i0 = (x * 16 + y) * 16 + z;
      int i1 = (x * 16 + y) * 16 + zp;
      f0a = dense[i0];
      f1a = dense[4096 + i0];
      f0b = dense[i1];
      f1b = dense[4096 + i1];
    } else {
      const float* tb = tables + (size_t)(lvl - 1) * (2 * TS);
      unsigned h0 = ((unsigned)x ^ ((unsigned)y * P2) ^ ((unsigned)z * P3)) & TMASK;
      unsigned h1 = ((unsigned)x ^ ((unsigned)y * P2) ^ ((unsigned)zp * P3)) & TMASK;
      f0a = tb[h0];
      f1a = tb[TS + h0];
      f0b = tb[h1];
      f1b = tb[TS + h1];
    }
    ws4[i] = make_float4(f0a, f1a, f0b, f1b);
  } else {
    int i2 = i - N4;
    if (i2 < 9 * TS) {
      int l = i2 >> 18;          // 0..8 -> levels 7..15 (table index 6+l)
      int h = i2 & TMASK;
      const float* tb = tables + (size_t)(l + 6) * (2 * TS);
      float2* ws2 = (float2*)(ws4 + N4);
      ws2[i2] = make_float2(tb[h], tb[TS + h]);
    }
  }
}

// Main kernel: thread = point; levels in sequence with a per-level barrier so
// resident waves gather from (roughly) one table at a time -> per-XCD L2 keeps
// the current table resident. Levels 0..6 use z-paired dense tables (4x16B
// gathers instead of 8x8B). Output via nontemporal stores (don't evict tables).
template <bool XP>
__global__ __launch_bounds__(256) void encode_kernel(
    const float* __restrict__ coords,
    const float* __restrict__ dense,       // original [2,16,16,16] (fallback)
    const float* __restrict__ tables,      // original [15,2,TS]    (fallback)
    const float4* __restrict__ xt4,        // workspace (XP path)
    float4* __restrict__ out, int npts) {
  constexpr int RESA[16] = {16, 20, 25, 32, 40, 50, 64, 80,
                            101, 128, 161, 203, 256, 322, 406, 512};
  constexpr int OFF4[7] = {0, 4096, 12096, 27721, 60489, 124489, 249489};
  __shared__ float s_c[768];   // 256 points x 3 coords
  const int tid = threadIdx.x;
  const int pbase = blockIdx.x * 256;

  // Coalesced coord staging: s_c[k] = coords[pbase*3 + k]
#pragma unroll
  for (int j = 0; j < 3; ++j) {
    int gi = pbase * 3 + j * 256 + tid;
    s_c[j * 256 + tid] = (gi < npts * 3) ? __builtin_nontemporal_load(&coords[gi]) : 0.0f;
  }
  __syncthreads();

  const int n = pbase + tid;
  const bool valid = n < npts;
  // stride-3 LDS read: 2-way bank aliasing only (free on gfx950)
  const float cxn = (s_c[tid * 3 + 0] + 1.0f) * 0.5f;
  const float cyn = (s_c[tid * 3 + 1] + 1.0f) * 0.5f;
  const float czn = (s_c[tid * 3 + 2] + 1.0f) * 0.5f;

  float acc[32];

#pragma unroll
  for (int lvl = 0; lvl < 16; ++lvl) {
    const int res = RESA[lvl];
    const int r1 = res - 1;
    const float rm1 = (float)r1;

    float px = fminf(fmaxf(cxn * rm1, 0.0f), rm1);
    float py = fminf(fmaxf(cyn * rm1, 0.0f), rm1);
    float pz = fminf(fmaxf(czn * rm1, 0.0f), rm1);
    float fx = floorf(px), fy = floorf(py), fz = floorf(pz);
    float wx = px - fx, wy = py - fy, wz = pz - fz;
    int ix0 = (int)fx, iy0 = (int)fy, iz0 = (int)fz;
    int ix1 = min(ix0 + 1, r1), iy1 = min(iy0 + 1, r1);

    float a0 = 0.0f, a1 = 0.0f;
    if (XP && lvl < 7) {
      // Dense z-paired path: 4 x 16B gathers, two z-corners per load.
      const float4* __restrict__ tab = xt4 + OFF4[lvl];
      int b00 = (ix0 * res + iy0) * res + iz0;
      int b01 = (ix0 * res + iy1) * res + iz0;
      int b10 = (ix1 * res + iy0) * res + iz0;
      int b11 = (ix1 * res + iy1) * res + iz0;
      float4 v00 = tab[b00];
      float4 v01 = tab[b01];
      float4 v10 = tab[b10];
      float4 v11 = tab[b11];
      float w00 = (1.0f - wx) * (1.0f - wy), w01 = (1.0f - wx) * wy;
      float w10 = wx * (1.0f - wy), w11 = wx * wy;
      float z0 = 1.0f - wz, z1 = wz;
      a0 = v00.x * (w00 * z0);            a1 = v00.y * (w00 * z0);
      a0 = fmaf(v00.z, w00 * z1, a0);     a1 = fmaf(v00.w, w00 * z1, a1);
      a0 = fmaf(v01.x, w01 * z0, a0);     a1 = fmaf(v01.y, w01 * z0, a1);
      a0 = fmaf(v01.z, w01 * z1, a0);     a1 = fmaf(v01.w, w01 * z1, a1);
      a0 = fmaf(v10.x, w10 * z0, a0);     a1 = fmaf(v10.y, w10 * z0, a1);
      a0 = fmaf(v10.z, w10 * z1, a0);     a1 = fmaf(v10.w, w10 * z1, a1);
      a0 = fmaf(v11.x, w11 * z0, a0);     a1 = fmaf(v11.y, w11 * z0, a1);
      a0 = fmaf(v11.z, w11 * z1, a0);     a1 = fmaf(v11.w, w11 * z1, a1);
    } else {
      int iz1 = min(iz0 + 1, r1);
      // Per-dim hash partials. Level 0 (dense, fallback only): disjoint bit
      // fields so XOR == ADD.
      unsigned hx0, hx1, hy0, hy1, hz0, hz1;
      if (lvl == 0) {
        hx0 = (unsigned)ix0 << 8; hx1 = (unsigned)ix1 << 8;
        hy0 = (unsigned)iy0 << 4; hy1 = (unsigned)iy1 << 4;
        hz0 = (unsigned)iz0;      hz1 = (unsigned)iz1;
      } else {
        hx0 = (unsigned)ix0;      hx1 = (unsigned)ix1;      // prime[0] = 1
        hy0 = (unsigned)iy0 * P2; hy1 = (unsigned)iy1 * P2;
        hz0 = (unsigned)iz0 * P3; hz1 = (unsigned)iz1 * P3;
      }

      unsigned idx[8];
      float wgt[8];
#pragma unroll
      for (int c = 0; c < 8; ++c) {
        unsigned hx = (c & 4) ? hx1 : hx0;
        unsigned hy = (c & 2) ? hy1 : hy0;
        unsigned hz = (c & 1) ? hz1 : hz0;
        idx[c] = (hx ^ hy ^ hz) & TMASK;
        float a = (c & 4) ? wx : 1.0f - wx;
        float b = (c & 2) ? wy : 1.0f - wy;
        float d = (c & 1) ? wz : 1.0f - wz;
        wgt[c] = a * b * d;
      }

      if (XP) {
        const float2* __restrict__ tab =
            ((const float2*)(xt4 + N4)) + (size_t)(lvl - 7) * TS;
        float2 v[8];
#pragma unroll
        for (int c = 0; c < 8; ++c) v[c] = tab[idx[c]];
#pragma unroll
        for (int c = 0; c < 8; ++c) {
          a0 = fmaf(v[c].x, wgt[c], a0);
          a1 = fmaf(v[c].y, wgt[c], a1);
        }
      } else {
        const float* t0 = (lvl == 0) ? dense : (tables + (size_t)(lvl - 1) * (2 * TS));
        const unsigned fs = (lvl == 0) ? 4096u : (unsigned)TS;
        float v0[8], v1[8];
#pragma unroll
        for (int c = 0; c < 8; ++c) { v0[c] = t0[idx[c]]; v1[c] = t0[fs + idx[c]]; }
#pragma unroll
        for (int c = 0; c < 8; ++c) {
          a0 = fmaf(v0[c], wgt[c], a0);
          a1 = fmaf(v1[c], wgt[c], a1);
        }
      }
    }
    acc[2 * lvl + 0] = a0;
    acc[2 * lvl + 1] = a1;

    // Keep the block's waves lockstepped on the level sequence so the
    // CU/XCD-level instantaneous table working set stays ~one level.
    __syncthreads();
  }

  if (valid) {
    nfloat4* o = (nfloat4*)(out + (size_t)n * 8);   // 128B contiguous row per thread
#pragma unroll
    for (int j = 0; j < 8; ++j) {
      nfloat4 v = {acc[4 * j + 0], acc[4 * j + 1], acc[4 * j + 2], acc[4 * j + 3]};
      __builtin_nontemporal_store(v, o + j);
    }
  }
}

extern "C" void kernel_launch(void* const* d_in, const int* in_sizes, int n_in,
                              void* d_out, int out_size, void* d_ws, size_t ws_size,
                              hipStream_t stream) {
  const float* coords = (const float*)d_in[0];
  const float* dense  = (const float*)d_in[1];
  const float* tables = (const float*)d_in[2];
  float4* out = (float4*)d_out;
  const int npts = in_sizes[0] / 3;
  const int eblocks = (npts + 255) / 256;
  const size_t need = (size_t)N4 * sizeof(float4) + (size_t)9 * TS * sizeof(float2);

  if (ws_size >= need) {
    float4* ws4 = (float4*)d_ws;
    const int total = N4 + 9 * TS;
    const int tblocks = (total + 255) / 256;
    hipLaunchKernelGGL(build_kernel, dim3(tblocks), dim3(256), 0, stream,
                       dense, tables, ws4);
    hipLaunchKernelGGL((encode_kernel<true>), dim3(eblocks), dim3(256), 0, stream,
                       coords, dense, tables, ws4, out, npts);
  } else {
    hipLaunchKernelGGL((encode_kernel<false>), dim3(eblocks), dim3(256), 0, stream,
                       coords, dense, tables, (const float4*)nullptr, out, npts);
  }
}